// Round 5
// baseline (702.625 us; speedup 1.0000x reference)
//
#include <hip/hip_runtime.h>

#define NFEAT 128
#define HID 64

// ================= CSR build =================
// Packed histogram: one u64 atomic per edge.
// high 24 bits: in-degree count; low 40 bits: sum of ew in 2^-24 fixed point.

__global__ __launch_bounds__(256) void k_init64(unsigned long long* pack, int n) {
    int i = blockIdx.x * 256 + threadIdx.x;
    if (i < n) pack[i] = 0ULL;
}

__global__ __launch_bounds__(256) void k_hist(const int* __restrict__ dst,
                                              const float* __restrict__ ew,
                                              unsigned long long* pack, int ne) {
    int e = blockIdx.x * 256 + threadIdx.x;
    if (e < ne) {
        unsigned long long q = (unsigned long long)__float2uint_rn(ew[e] * 16777216.0f);
        atomicAdd(&pack[dst[e]], (1ULL << 40) | q);
    }
}

__global__ __launch_bounds__(256) void k_unpack(const unsigned long long* __restrict__ pack,
                                                float* __restrict__ dis,
                                                int* __restrict__ offs, int n) {
    int i = blockIdx.x * 256 + threadIdx.x;
    if (i < n) {
        unsigned long long p = pack[i];
        offs[i] = (int)(p >> 40);
        float deg = 1.0f + (float)((double)(p & 0xFFFFFFFFFFULL) * (1.0 / 16777216.0));
        dis[i] = rsqrtf(deg);
    }
}

// ---------------- exclusive scan of offs (in place) ----------------

__global__ __launch_bounds__(256) void k_scanA(int* offs, int* part, int n) {
    __shared__ int tmp[256];
    int tid = threadIdx.x;
    int i = blockIdx.x * 256 + tid;
    int v = (i < n) ? offs[i] : 0;
    tmp[tid] = v;
    __syncthreads();
    for (int d = 1; d < 256; d <<= 1) {
        int a = (tid >= d) ? tmp[tid - d] : 0;
        __syncthreads();
        tmp[tid] += a;
        __syncthreads();
    }
    if (i < n) offs[i] = tmp[tid] - v;  // exclusive
    if (tid == 255) part[blockIdx.x] = tmp[255];
}

__global__ __launch_bounds__(512) void k_scanB(int* part, int nb) {
    __shared__ int tmp[512];
    int tid = threadIdx.x;
    int v = (tid < nb) ? part[tid] : 0;
    tmp[tid] = v;
    __syncthreads();
    for (int d = 1; d < 512; d <<= 1) {
        int a = (tid >= d) ? tmp[tid - d] : 0;
        __syncthreads();
        tmp[tid] += a;
        __syncthreads();
    }
    if (tid < nb) part[tid] = tmp[tid] - v;  // exclusive
}

__global__ __launch_bounds__(256) void k_scanC(int* offs, const int* __restrict__ part, int n) {
    int i = blockIdx.x * 256 + threadIdx.x;
    if (i < n) offs[i] += part[blockIdx.x];
}

// CSR fill: one atomic + one 8B store per edge. After this, offs[i] == row end.

__global__ __launch_bounds__(256) void k_fill(const int* __restrict__ src,
                                              const int* __restrict__ dst,
                                              const float* __restrict__ ew,
                                              const float* __restrict__ dis,
                                              int* offs, int2* __restrict__ csr, int ne) {
    int e = blockIdx.x * 256 + threadIdx.x;
    if (e < ne) {
        int s = src[e], d = dst[e];
        int slot = atomicAdd(&offs[d], 1);
        float nrm = dis[s] * ew[e] * dis[d];
        csr[slot] = make_int2(s, __float_as_int(nrm));
    }
}

// ================= dense transform xw = x @ W^T (W [HID][K] row-major) ======
// thread = (row, output-quad q). 16 q-lanes of a row read the SAME x quad
// (broadcast); W quads are L1-hot. acc = 4 VGPRs -> high occupancy.

template <int K>
__global__ __launch_bounds__(256) void k_xw(const float* __restrict__ x,
                                            const float* __restrict__ W,
                                            float* __restrict__ out, int M) {
    int tid = threadIdx.x;
    int q = tid & 15;
    int row = blockIdx.x * 16 + (tid >> 4);
    if (row >= M) return;

    const float4* xr = (const float4*)(x + (size_t)row * K);
    const float4* Wr = (const float4*)W;

    float4 acc = make_float4(0.f, 0.f, 0.f, 0.f);
#pragma unroll
    for (int kc = 0; kc < K / 4; ++kc) {
        float4 xv = xr[kc];
        float4 w0 = Wr[(4 * q + 0) * (K / 4) + kc];
        float4 w1 = Wr[(4 * q + 1) * (K / 4) + kc];
        float4 w2 = Wr[(4 * q + 2) * (K / 4) + kc];
        float4 w3 = Wr[(4 * q + 3) * (K / 4) + kc];
        acc.x = fmaf(xv.x, w0.x, fmaf(xv.y, w0.y, fmaf(xv.z, w0.z, fmaf(xv.w, w0.w, acc.x))));
        acc.y = fmaf(xv.x, w1.x, fmaf(xv.y, w1.y, fmaf(xv.z, w1.z, fmaf(xv.w, w1.w, acc.y))));
        acc.z = fmaf(xv.x, w2.x, fmaf(xv.y, w2.y, fmaf(xv.z, w2.z, fmaf(xv.w, w2.w, acc.z))));
        acc.w = fmaf(xv.x, w3.x, fmaf(xv.y, w3.y, fmaf(xv.z, w3.z, fmaf(xv.w, w3.w, acc.w))));
    }
    ((float4*)(out + (size_t)row * HID))[q] = acc;
}

// ===== gather core (float4-lane): lane = (edge-slot l>>4, feature-quad l&15) =

__device__ __forceinline__ float4 gather_row(const float4* __restrict__ xw4,
                                             const float* __restrict__ dis,
                                             const int* __restrict__ offs,
                                             const int2* __restrict__ csr,
                                             int i, int eslot, int fq) {
    float di = dis[i];
    float4 acc = make_float4(0.f, 0.f, 0.f, 0.f);
    if (eslot == 0) {
        float4 sv = xw4[(size_t)i * 16 + fq];
        float s = di * di;
        acc = make_float4(s * sv.x, s * sv.y, s * sv.z, s * sv.w);
    }
    int beg = (i == 0) ? 0 : offs[i - 1];
    int end = offs[i];
    for (int e = beg; e < end; e += 8) {
        int e0 = e + eslot, e1 = e0 + 4;
        int i0 = (e0 < end) ? e0 : beg;
        int i1 = (e1 < end) ? e1 : beg;
        int2 c0 = csr[i0];
        int2 c1 = csr[i1];
        float n0 = (e0 < end) ? __int_as_float(c0.y) : 0.0f;
        float n1 = (e1 < end) ? __int_as_float(c1.y) : 0.0f;
        float4 v0 = xw4[(size_t)c0.x * 16 + fq];
        float4 v1 = xw4[(size_t)c1.x * 16 + fq];
        acc.x = fmaf(n0, v0.x, acc.x);
        acc.y = fmaf(n0, v0.y, acc.y);
        acc.z = fmaf(n0, v0.z, acc.z);
        acc.w = fmaf(n0, v0.w, acc.w);
        acc.x = fmaf(n1, v1.x, acc.x);
        acc.y = fmaf(n1, v1.y, acc.y);
        acc.z = fmaf(n1, v1.z, acc.z);
        acc.w = fmaf(n1, v1.w, acc.w);
    }
    acc.x += __shfl_xor(acc.x, 16, 64);
    acc.y += __shfl_xor(acc.y, 16, 64);
    acc.z += __shfl_xor(acc.z, 16, 64);
    acc.w += __shfl_xor(acc.w, 16, 64);
    acc.x += __shfl_xor(acc.x, 32, 64);
    acc.y += __shfl_xor(acc.y, 32, 64);
    acc.z += __shfl_xor(acc.z, 32, 64);
    acc.w += __shfl_xor(acc.w, 32, 64);
    return acc;
}

// ===== gather layer1 (+b1, relu) fused with xw2 = h1 @ W2^T ==================

__global__ __launch_bounds__(256) void k_gather_fuse(const float* __restrict__ xw,
                                                     const float* __restrict__ dis,
                                                     const int* __restrict__ offs,
                                                     const int2* __restrict__ csr,
                                                     const float* __restrict__ b1,
                                                     const float* __restrict__ W2,
                                                     float* __restrict__ out, int n) {
    __shared__ float W2T[HID * 65];
    for (int idx = threadIdx.x; idx < HID * HID; idx += 256) {
        int hp = idx >> 6, h = idx & 63;
        W2T[h * 65 + hp] = W2[idx];  // W2T[h][h'] = W2[h'][h]
    }
    __syncthreads();

    int lane  = threadIdx.x & 63;
    int eslot = lane >> 4;
    int fq    = lane & 15;
    int wid = blockIdx.x * 4 + (threadIdx.x >> 6);
    int nw  = gridDim.x * 4;
    const float4* xw4 = (const float4*)xw;
    float4 bq = ((const float4*)b1)[fq];

    for (int i = wid; i < n; i += nw) {
        float4 acc = gather_row(xw4, dis, offs, csr, i, eslot, fq);
        float4 h1;
        h1.x = fmaxf(acc.x + bq.x, 0.0f);
        h1.y = fmaxf(acc.y + bq.y, 0.0f);
        h1.z = fmaxf(acc.z + bq.z, 0.0f);
        h1.w = fmaxf(acc.w + bq.w, 0.0f);

        float acc2 = 0.0f;
#pragma unroll
        for (int hg = 0; hg < 16; ++hg) {
            float hx = __shfl(h1.x, hg, 64);
            float hy = __shfl(h1.y, hg, 64);
            float hz = __shfl(h1.z, hg, 64);
            float hw = __shfl(h1.w, hg, 64);
            acc2 = fmaf(hx, W2T[(4 * hg + 0) * 65 + lane], acc2);
            acc2 = fmaf(hy, W2T[(4 * hg + 1) * 65 + lane], acc2);
            acc2 = fmaf(hz, W2T[(4 * hg + 2) * 65 + lane], acc2);
            acc2 = fmaf(hw, W2T[(4 * hg + 3) * 65 + lane], acc2);
        }
        out[(size_t)i * HID + lane] = acc2;
    }
}

// ===== gather layer2 (+b2, relu) fused with head (.W3 + b3) ==================

__global__ __launch_bounds__(256) void k_gather_final(const float* __restrict__ xw,
                                                      const float* __restrict__ dis,
                                                      const int* __restrict__ offs,
                                                      const int2* __restrict__ csr,
                                                      const float* __restrict__ b2,
                                                      const float* __restrict__ W3,
                                                      const float* __restrict__ b3,
                                                      float* __restrict__ out, int n) {
    int lane  = threadIdx.x & 63;
    int eslot = lane >> 4;
    int fq    = lane & 15;
    int wid = blockIdx.x * 4 + (threadIdx.x >> 6);
    int nw  = gridDim.x * 4;
    const float4* xw4 = (const float4*)xw;
    float4 bq = ((const float4*)b2)[fq];
    float4 wq = ((const float4*)W3)[fq];
    float bb3 = b3[0];

    for (int i = wid; i < n; i += nw) {
        float4 acc = gather_row(xw4, dis, offs, csr, i, eslot, fq);
        float p = fmaxf(acc.x + bq.x, 0.0f) * wq.x
                + fmaxf(acc.y + bq.y, 0.0f) * wq.y
                + fmaxf(acc.z + bq.z, 0.0f) * wq.z
                + fmaxf(acc.w + bq.w, 0.0f) * wq.w;
        p += __shfl_xor(p, 1, 64);
        p += __shfl_xor(p, 2, 64);
        p += __shfl_xor(p, 4, 64);
        p += __shfl_xor(p, 8, 64);
        if (lane == 0) out[i] = p + bb3;
    }
}

// ================= fallback (atomic scatter) =================

__global__ __launch_bounds__(256) void k_deg_init1(float* deg, int n) {
    int i = blockIdx.x * 256 + threadIdx.x;
    if (i < n) deg[i] = 1.0f;
}

__global__ __launch_bounds__(256) void k_deg_accum(const int* __restrict__ dst,
                                                   const float* __restrict__ ew,
                                                   float* deg, int ne) {
    int e = blockIdx.x * 256 + threadIdx.x;
    if (e < ne) atomicAdd(&deg[dst[e]], ew[e]);
}

__global__ __launch_bounds__(256) void k_rsqrt(float* deg, int n) {
    int i = blockIdx.x * 256 + threadIdx.x;
    if (i < n) deg[i] = rsqrtf(deg[i]);
}

__global__ __launch_bounds__(256) void k_selfinit(const float* __restrict__ xw,
                                                  const float* __restrict__ dis,
                                                  float* __restrict__ agg, int n) {
    int idx = blockIdx.x * 256 + threadIdx.x;
    if (idx < n * 16) {
        int i = idx >> 4;
        float d = dis[i];
        float s = d * d;
        float4 v = ((const float4*)xw)[idx];
        ((float4*)agg)[idx] = make_float4(s * v.x, s * v.y, s * v.z, s * v.w);
    }
}

__global__ __launch_bounds__(256) void k_scatter(const int* __restrict__ src,
                                                 const int* __restrict__ dst,
                                                 const float* __restrict__ ew,
                                                 const float* __restrict__ dis,
                                                 const float* __restrict__ xw,
                                                 float* __restrict__ agg, int ne) {
    int t = threadIdx.x;
    int e = blockIdx.x * 4 + (t >> 6);
    if (e >= ne) return;
    int s = src[e], d = dst[e];
    float nrm = dis[s] * ew[e] * dis[d];
    int h = t & 63;
    atomicAdd(&agg[(size_t)d * HID + h], nrm * xw[(size_t)s * HID + h]);
}

__global__ __launch_bounds__(256) void k_bias_relu(float* __restrict__ agg,
                                                   const float* __restrict__ b, int n) {
    int idx = blockIdx.x * 256 + threadIdx.x;
    if (idx < n * 16) {
        int hq = idx & 15;
        float4 v = ((float4*)agg)[idx];
        float4 bb = ((const float4*)b)[hq];
        v.x = fmaxf(v.x + bb.x, 0.0f);
        v.y = fmaxf(v.y + bb.y, 0.0f);
        v.z = fmaxf(v.z + bb.z, 0.0f);
        v.w = fmaxf(v.w + bb.w, 0.0f);
        ((float4*)agg)[idx] = v;
    }
}

__global__ __launch_bounds__(256) void k_final(const float* __restrict__ agg,
                                               const float* __restrict__ b2,
                                               const float* __restrict__ W3,
                                               const float* __restrict__ b3,
                                               float* __restrict__ out, int n) {
    int t = threadIdx.x;
    int i = blockIdx.x * 4 + (t >> 6);
    if (i >= n) return;
    int h = t & 63;
    float v = fmaxf(agg[(size_t)i * HID + h] + b2[h], 0.0f) * W3[h];
#pragma unroll
    for (int off = 32; off > 0; off >>= 1) v += __shfl_down(v, off, 64);
    if (h == 0) out[i] = v + b3[0];
}

// ================= launch =================

extern "C" void kernel_launch(void* const* d_in, const int* in_sizes, int n_in,
                              void* d_out, int out_size, void* d_ws, size_t ws_size,
                              hipStream_t stream) {
    const float* x  = (const float*)d_in[0];
    const int*   ei = (const int*)d_in[1];
    const float* ew = (const float*)d_in[2];
    const float* W1 = (const float*)d_in[4];
    const float* b1 = (const float*)d_in[5];
    const float* W2 = (const float*)d_in[6];
    const float* b2 = (const float*)d_in[7];
    const float* W3 = (const float*)d_in[8];
    const float* b3 = (const float*)d_in[9];
    float* out = (float*)d_out;

    int N = in_sizes[0] / NFEAT;
    int E = in_sizes[1] / 2;
    const int* src = ei;
    const int* dst = ei + E;

    dim3 blk(256);
    int gN  = (N + 255) / 256;
    int gE  = (E + 255) / 256;
    int gXW = (N + 15) / 16;   // 16 rows per block in k_xw

    size_t offA   = 0;                            // N*HID f32  (pack: N u64 at head)
    size_t offB   = offA + (size_t)N * HID * 4;   // N*HID f32
    size_t offDis = offB + (size_t)N * HID * 4;   // N f32
    size_t offOff = offDis + (size_t)N * 4;       // N i32
    size_t offPar = offOff + (size_t)N * 4;       // 512 i32
    size_t offCSR = offPar + 512 * 4;             // E int2
    size_t need   = offCSR + (size_t)E * 8;

    char* ws = (char*)d_ws;
    float* bufA = (float*)(ws + offA);
    float* bufB = (float*)(ws + offB);
    float* dis  = (float*)(ws + offDis);

    if (ws_size >= need) {
        unsigned long long* pack = (unsigned long long*)bufA;  // dead before k_xw writes bufA
        int*  offs = (int*)(ws + offOff);
        int*  part = (int*)(ws + offPar);
        int2* csr  = (int2*)(ws + offCSR);

        // CSR build (shared by both layers)
        k_init64<<<gN, blk, 0, stream>>>(pack, N);
        k_hist<<<gE, blk, 0, stream>>>(dst, ew, pack, E);
        k_unpack<<<gN, blk, 0, stream>>>(pack, dis, offs, N);
        k_scanA<<<gN, blk, 0, stream>>>(offs, part, N);
        k_scanB<<<1, dim3(512), 0, stream>>>(part, gN);
        k_scanC<<<gN, blk, 0, stream>>>(offs, part, N);
        k_fill<<<gE, blk, 0, stream>>>(src, dst, ew, dis, offs, csr, E);

        // layer 1 transform, then gather1+relu+xw2 fused, then gather2+head
        k_xw<NFEAT><<<gXW, blk, 0, stream>>>(x, W1, bufA, N);
        k_gather_fuse<<<2048, blk, 0, stream>>>(bufA, dis, offs, csr, b1, W2, bufB, N);
        k_gather_final<<<2048, blk, 0, stream>>>(bufB, dis, offs, csr, b2, W3, b3, out, N);
    } else {
        // fallback: atomic scatter path
        int gNH4 = (N * 16 + 255) / 256;
        int gE4  = (E + 3) / 4;
        int gN4  = (N + 3) / 4;
        k_deg_init1<<<gN, blk, 0, stream>>>(dis, N);
        k_deg_accum<<<gE, blk, 0, stream>>>(dst, ew, dis, E);
        k_rsqrt<<<gN, blk, 0, stream>>>(dis, N);

        k_xw<NFEAT><<<gXW, blk, 0, stream>>>(x, W1, bufA, N);
        k_selfinit<<<gNH4, blk, 0, stream>>>(bufA, dis, bufB, N);
        k_scatter<<<gE4, blk, 0, stream>>>(src, dst, ew, dis, bufA, bufB, E);
        k_bias_relu<<<gNH4, blk, 0, stream>>>(bufB, b1, N);

        k_xw<HID><<<gXW, blk, 0, stream>>>(bufB, W2, bufA, N);
        k_selfinit<<<gNH4, blk, 0, stream>>>(bufA, dis, bufB, N);
        k_scatter<<<gE4, blk, 0, stream>>>(src, dst, ew, dis, bufA, bufB, E);
        k_final<<<gN4, blk, 0, stream>>>(bufB, b2, W3, b3, out, N);
    }
}

// Round 6
// 389.924 us; speedup vs baseline: 1.8020x; 1.8020x over previous
//
#include <hip/hip_runtime.h>

#define NFEAT 128
#define HID 64

// ================= CSR build =================
// Packed histogram: one u64 atomic per edge.
// high 24 bits: in-degree count; low 40 bits: sum of ew in 2^-24 fixed point.

__global__ __launch_bounds__(256) void k_init64(unsigned long long* pack, int n) {
    int i = blockIdx.x * 256 + threadIdx.x;
    if (i < n) pack[i] = 0ULL;
}

__global__ __launch_bounds__(256) void k_hist(const int* __restrict__ dst,
                                              const float* __restrict__ ew,
                                              unsigned long long* pack, int ne) {
    int e = blockIdx.x * 256 + threadIdx.x;
    if (e < ne) {
        unsigned long long q = (unsigned long long)__float2uint_rn(ew[e] * 16777216.0f);
        atomicAdd(&pack[dst[e]], (1ULL << 40) | q);
    }
}

__global__ __launch_bounds__(256) void k_unpack(const unsigned long long* __restrict__ pack,
                                                float* __restrict__ dis,
                                                int* __restrict__ offs, int n) {
    int i = blockIdx.x * 256 + threadIdx.x;
    if (i < n) {
        unsigned long long p = pack[i];
        offs[i] = (int)(p >> 40);
        float deg = 1.0f + (float)((double)(p & 0xFFFFFFFFFFULL) * (1.0 / 16777216.0));
        dis[i] = rsqrtf(deg);
    }
}

// ---------------- exclusive scan of offs (in place) ----------------

__global__ __launch_bounds__(256) void k_scanA(int* offs, int* part, int n) {
    __shared__ int tmp[256];
    int tid = threadIdx.x;
    int i = blockIdx.x * 256 + tid;
    int v = (i < n) ? offs[i] : 0;
    tmp[tid] = v;
    __syncthreads();
    for (int d = 1; d < 256; d <<= 1) {
        int a = (tid >= d) ? tmp[tid - d] : 0;
        __syncthreads();
        tmp[tid] += a;
        __syncthreads();
    }
    if (i < n) offs[i] = tmp[tid] - v;  // exclusive
    if (tid == 255) part[blockIdx.x] = tmp[255];
}

__global__ __launch_bounds__(512) void k_scanB(int* part, int nb) {
    __shared__ int tmp[512];
    int tid = threadIdx.x;
    int v = (tid < nb) ? part[tid] : 0;
    tmp[tid] = v;
    __syncthreads();
    for (int d = 1; d < 512; d <<= 1) {
        int a = (tid >= d) ? tmp[tid - d] : 0;
        __syncthreads();
        tmp[tid] += a;
        __syncthreads();
    }
    if (tid < nb) part[tid] = tmp[tid] - v;  // exclusive
}

__global__ __launch_bounds__(256) void k_scanC(int* offs, const int* __restrict__ part, int n) {
    int i = blockIdx.x * 256 + threadIdx.x;
    if (i < n) offs[i] += part[blockIdx.x];
}

// CSR fill: one atomic + one 8B store per edge. After this, offs[i] == row end.

__global__ __launch_bounds__(256) void k_fill(const int* __restrict__ src,
                                              const int* __restrict__ dst,
                                              const float* __restrict__ ew,
                                              const float* __restrict__ dis,
                                              int* offs, int2* __restrict__ csr, int ne) {
    int e = blockIdx.x * 256 + threadIdx.x;
    if (e < ne) {
        int s = src[e], d = dst[e];
        int slot = atomicAdd(&offs[d], 1);
        float nrm = dis[s] * ew[e] * dis[d];
        csr[slot] = make_int2(s, __float_as_int(nrm));
    }
}

// ================= dense transform xw = x @ W^T (W [HID][K] row-major) ======
// Block = 4 waves; wave cg owns output colgroup cg (16 cols) -> W address is
// wave-uniform (readfirstlane) -> scalar s_load path, 1 transaction.
// lane = row within the block's 64-row strip; acc[16] keeps VGPRs low.

template <int K>
__global__ __launch_bounds__(256) void k_xw(const float* __restrict__ x,
                                            const float* __restrict__ W,
                                            float* __restrict__ out, int M) {
    int lane = threadIdx.x & 63;
    int cg = __builtin_amdgcn_readfirstlane(threadIdx.x >> 6);  // 0..3, wave-uniform
    int row = blockIdx.x * 64 + lane;
    if (row >= M) return;

    const float4* xr = (const float4*)(x + (size_t)row * K);
    const float4* Wr = (const float4*)(W + (size_t)cg * 16 * K);  // 16 W rows

    float acc[16];
#pragma unroll
    for (int h = 0; h < 16; ++h) acc[h] = 0.0f;

#pragma unroll 4
    for (int kc = 0; kc < K / 4; ++kc) {
        float4 xv = xr[kc];
#pragma unroll
        for (int h = 0; h < 16; ++h) {
            float4 wv = Wr[h * (K / 4) + kc];
            acc[h] = fmaf(xv.x, wv.x, acc[h]);
            acc[h] = fmaf(xv.y, wv.y, acc[h]);
            acc[h] = fmaf(xv.z, wv.z, acc[h]);
            acc[h] = fmaf(xv.w, wv.w, acc[h]);
        }
    }

    float4* o = (float4*)(out + (size_t)row * HID + cg * 16);
#pragma unroll
    for (int q = 0; q < 4; ++q)
        o[q] = make_float4(acc[4 * q], acc[4 * q + 1], acc[4 * q + 2], acc[4 * q + 3]);
}

// ===== gather core (float4-lane): lane = (edge-slot l>>4, feature-quad l&15) =

__device__ __forceinline__ float4 gather_row(const float4* __restrict__ xw4,
                                             const float* __restrict__ dis,
                                             const int* __restrict__ offs,
                                             const int2* __restrict__ csr,
                                             int i, int eslot, int fq) {
    float di = dis[i];
    float4 acc = make_float4(0.f, 0.f, 0.f, 0.f);
    if (eslot == 0) {
        float4 sv = xw4[(size_t)i * 16 + fq];
        float s = di * di;
        acc = make_float4(s * sv.x, s * sv.y, s * sv.z, s * sv.w);
    }
    int beg = (i == 0) ? 0 : offs[i - 1];
    int end = offs[i];
    for (int e = beg; e < end; e += 8) {
        int e0 = e + eslot, e1 = e0 + 4;
        int i0 = (e0 < end) ? e0 : beg;
        int i1 = (e1 < end) ? e1 : beg;
        int2 c0 = csr[i0];
        int2 c1 = csr[i1];
        float n0 = (e0 < end) ? __int_as_float(c0.y) : 0.0f;
        float n1 = (e1 < end) ? __int_as_float(c1.y) : 0.0f;
        float4 v0 = xw4[(size_t)c0.x * 16 + fq];
        float4 v1 = xw4[(size_t)c1.x * 16 + fq];
        acc.x = fmaf(n0, v0.x, acc.x);
        acc.y = fmaf(n0, v0.y, acc.y);
        acc.z = fmaf(n0, v0.z, acc.z);
        acc.w = fmaf(n0, v0.w, acc.w);
        acc.x = fmaf(n1, v1.x, acc.x);
        acc.y = fmaf(n1, v1.y, acc.y);
        acc.z = fmaf(n1, v1.z, acc.z);
        acc.w = fmaf(n1, v1.w, acc.w);
    }
    acc.x += __shfl_xor(acc.x, 16, 64);
    acc.y += __shfl_xor(acc.y, 16, 64);
    acc.z += __shfl_xor(acc.z, 16, 64);
    acc.w += __shfl_xor(acc.w, 16, 64);
    acc.x += __shfl_xor(acc.x, 32, 64);
    acc.y += __shfl_xor(acc.y, 32, 64);
    acc.z += __shfl_xor(acc.z, 32, 64);
    acc.w += __shfl_xor(acc.w, 32, 64);
    return acc;
}

// ===== gather layer1 (+b1, relu) fused with xw2 = h1 @ W2^T ==================

__global__ __launch_bounds__(256) void k_gather_fuse(const float* __restrict__ xw,
                                                     const float* __restrict__ dis,
                                                     const int* __restrict__ offs,
                                                     const int2* __restrict__ csr,
                                                     const float* __restrict__ b1,
                                                     const float* __restrict__ W2,
                                                     float* __restrict__ out, int n) {
    __shared__ float W2T[HID * 65];
    for (int idx = threadIdx.x; idx < HID * HID; idx += 256) {
        int hp = idx >> 6, h = idx & 63;
        W2T[h * 65 + hp] = W2[idx];  // W2T[h][h'] = W2[h'][h]
    }
    __syncthreads();

    int lane  = threadIdx.x & 63;
    int eslot = lane >> 4;
    int fq    = lane & 15;
    int wid = blockIdx.x * 4 + (threadIdx.x >> 6);
    int nw  = gridDim.x * 4;
    const float4* xw4 = (const float4*)xw;
    float4 bq = ((const float4*)b1)[fq];

    for (int i = wid; i < n; i += nw) {
        float4 acc = gather_row(xw4, dis, offs, csr, i, eslot, fq);
        float4 h1;
        h1.x = fmaxf(acc.x + bq.x, 0.0f);
        h1.y = fmaxf(acc.y + bq.y, 0.0f);
        h1.z = fmaxf(acc.z + bq.z, 0.0f);
        h1.w = fmaxf(acc.w + bq.w, 0.0f);

        float acc2 = 0.0f;
#pragma unroll
        for (int hg = 0; hg < 16; ++hg) {
            float hx = __shfl(h1.x, hg, 64);
            float hy = __shfl(h1.y, hg, 64);
            float hz = __shfl(h1.z, hg, 64);
            float hw = __shfl(h1.w, hg, 64);
            acc2 = fmaf(hx, W2T[(4 * hg + 0) * 65 + lane], acc2);
            acc2 = fmaf(hy, W2T[(4 * hg + 1) * 65 + lane], acc2);
            acc2 = fmaf(hz, W2T[(4 * hg + 2) * 65 + lane], acc2);
            acc2 = fmaf(hw, W2T[(4 * hg + 3) * 65 + lane], acc2);
        }
        out[(size_t)i * HID + lane] = acc2;
    }
}

// ===== gather layer2 (+b2, relu) fused with head (.W3 + b3) ==================

__global__ __launch_bounds__(256) void k_gather_final(const float* __restrict__ xw,
                                                      const float* __restrict__ dis,
                                                      const int* __restrict__ offs,
                                                      const int2* __restrict__ csr,
                                                      const float* __restrict__ b2,
                                                      const float* __restrict__ W3,
                                                      const float* __restrict__ b3,
                                                      float* __restrict__ out, int n) {
    int lane  = threadIdx.x & 63;
    int eslot = lane >> 4;
    int fq    = lane & 15;
    int wid = blockIdx.x * 4 + (threadIdx.x >> 6);
    int nw  = gridDim.x * 4;
    const float4* xw4 = (const float4*)xw;
    float4 bq = ((const float4*)b2)[fq];
    float4 wq = ((const float4*)W3)[fq];
    float bb3 = b3[0];

    for (int i = wid; i < n; i += nw) {
        float4 acc = gather_row(xw4, dis, offs, csr, i, eslot, fq);
        float p = fmaxf(acc.x + bq.x, 0.0f) * wq.x
                + fmaxf(acc.y + bq.y, 0.0f) * wq.y
                + fmaxf(acc.z + bq.z, 0.0f) * wq.z
                + fmaxf(acc.w + bq.w, 0.0f) * wq.w;
        p += __shfl_xor(p, 1, 64);
        p += __shfl_xor(p, 2, 64);
        p += __shfl_xor(p, 4, 64);
        p += __shfl_xor(p, 8, 64);
        if (lane == 0) out[i] = p + bb3;
    }
}

// ================= fallback (atomic scatter) =================

__global__ __launch_bounds__(256) void k_deg_init1(float* deg, int n) {
    int i = blockIdx.x * 256 + threadIdx.x;
    if (i < n) deg[i] = 1.0f;
}

__global__ __launch_bounds__(256) void k_deg_accum(const int* __restrict__ dst,
                                                   const float* __restrict__ ew,
                                                   float* deg, int ne) {
    int e = blockIdx.x * 256 + threadIdx.x;
    if (e < ne) atomicAdd(&deg[dst[e]], ew[e]);
}

__global__ __launch_bounds__(256) void k_rsqrt(float* deg, int n) {
    int i = blockIdx.x * 256 + threadIdx.x;
    if (i < n) deg[i] = rsqrtf(deg[i]);
}

__global__ __launch_bounds__(256) void k_selfinit(const float* __restrict__ xw,
                                                  const float* __restrict__ dis,
                                                  float* __restrict__ agg, int n) {
    int idx = blockIdx.x * 256 + threadIdx.x;
    if (idx < n * 16) {
        int i = idx >> 4;
        float d = dis[i];
        float s = d * d;
        float4 v = ((const float4*)xw)[idx];
        ((float4*)agg)[idx] = make_float4(s * v.x, s * v.y, s * v.z, s * v.w);
    }
}

__global__ __launch_bounds__(256) void k_scatter(const int* __restrict__ src,
                                                 const int* __restrict__ dst,
                                                 const float* __restrict__ ew,
                                                 const float* __restrict__ dis,
                                                 const float* __restrict__ xw,
                                                 float* __restrict__ agg, int ne) {
    int t = threadIdx.x;
    int e = blockIdx.x * 4 + (t >> 6);
    if (e >= ne) return;
    int s = src[e], d = dst[e];
    float nrm = dis[s] * ew[e] * dis[d];
    int h = t & 63;
    atomicAdd(&agg[(size_t)d * HID + h], nrm * xw[(size_t)s * HID + h]);
}

__global__ __launch_bounds__(256) void k_bias_relu(float* __restrict__ agg,
                                                   const float* __restrict__ b, int n) {
    int idx = blockIdx.x * 256 + threadIdx.x;
    if (idx < n * 16) {
        int hq = idx & 15;
        float4 v = ((float4*)agg)[idx];
        float4 bb = ((const float4*)b)[hq];
        v.x = fmaxf(v.x + bb.x, 0.0f);
        v.y = fmaxf(v.y + bb.y, 0.0f);
        v.z = fmaxf(v.z + bb.z, 0.0f);
        v.w = fmaxf(v.w + bb.w, 0.0f);
        ((float4*)agg)[idx] = v;
    }
}

__global__ __launch_bounds__(256) void k_final(const float* __restrict__ agg,
                                               const float* __restrict__ b2,
                                               const float* __restrict__ W3,
                                               const float* __restrict__ b3,
                                               float* __restrict__ out, int n) {
    int t = threadIdx.x;
    int i = blockIdx.x * 4 + (t >> 6);
    if (i >= n) return;
    int h = t & 63;
    float v = fmaxf(agg[(size_t)i * HID + h] + b2[h], 0.0f) * W3[h];
#pragma unroll
    for (int off = 32; off > 0; off >>= 1) v += __shfl_down(v, off, 64);
    if (h == 0) out[i] = v + b3[0];
}

// ================= launch =================

extern "C" void kernel_launch(void* const* d_in, const int* in_sizes, int n_in,
                              void* d_out, int out_size, void* d_ws, size_t ws_size,
                              hipStream_t stream) {
    const float* x  = (const float*)d_in[0];
    const int*   ei = (const int*)d_in[1];
    const float* ew = (const float*)d_in[2];
    const float* W1 = (const float*)d_in[4];
    const float* b1 = (const float*)d_in[5];
    const float* W2 = (const float*)d_in[6];
    const float* b2 = (const float*)d_in[7];
    const float* W3 = (const float*)d_in[8];
    const float* b3 = (const float*)d_in[9];
    float* out = (float*)d_out;

    int N = in_sizes[0] / NFEAT;
    int E = in_sizes[1] / 2;
    const int* src = ei;
    const int* dst = ei + E;

    dim3 blk(256);
    int gN  = (N + 255) / 256;
    int gE  = (E + 255) / 256;
    int gXW = (N + 63) / 64;   // 64 rows per block in k_xw

    size_t offA   = 0;                            // N*HID f32  (pack: N u64 at head)
    size_t offB   = offA + (size_t)N * HID * 4;   // N*HID f32
    size_t offDis = offB + (size_t)N * HID * 4;   // N f32
    size_t offOff = offDis + (size_t)N * 4;       // N i32
    size_t offPar = offOff + (size_t)N * 4;       // 512 i32
    size_t offCSR = offPar + 512 * 4;             // E int2
    size_t need   = offCSR + (size_t)E * 8;

    char* ws = (char*)d_ws;
    float* bufA = (float*)(ws + offA);
    float* bufB = (float*)(ws + offB);
    float* dis  = (float*)(ws + offDis);

    if (ws_size >= need) {
        unsigned long long* pack = (unsigned long long*)bufA;  // dead before k_xw writes bufA
        int*  offs = (int*)(ws + offOff);
        int*  part = (int*)(ws + offPar);
        int2* csr  = (int2*)(ws + offCSR);

        // CSR build (shared by both layers)
        k_init64<<<gN, blk, 0, stream>>>(pack, N);
        k_hist<<<gE, blk, 0, stream>>>(dst, ew, pack, E);
        k_unpack<<<gN, blk, 0, stream>>>(pack, dis, offs, N);
        k_scanA<<<gN, blk, 0, stream>>>(offs, part, N);
        k_scanB<<<1, dim3(512), 0, stream>>>(part, gN);
        k_scanC<<<gN, blk, 0, stream>>>(offs, part, N);
        k_fill<<<gE, blk, 0, stream>>>(src, dst, ew, dis, offs, csr, E);

        // layer 1 transform, then gather1+relu+xw2 fused, then gather2+head
        k_xw<NFEAT><<<gXW, blk, 0, stream>>>(x, W1, bufA, N);
        k_gather_fuse<<<2048, blk, 0, stream>>>(bufA, dis, offs, csr, b1, W2, bufB, N);
        k_gather_final<<<2048, blk, 0, stream>>>(bufB, dis, offs, csr, b2, W3, b3, out, N);
    } else {
        // fallback: atomic scatter path
        int gNH4 = (N * 16 + 255) / 256;
        int gE4  = (E + 3) / 4;
        int gN4  = (N + 3) / 4;
        k_deg_init1<<<gN, blk, 0, stream>>>(dis, N);
        k_deg_accum<<<gE, blk, 0, stream>>>(dst, ew, dis, E);
        k_rsqrt<<<gN, blk, 0, stream>>>(dis, N);

        k_xw<NFEAT><<<gXW, blk, 0, stream>>>(x, W1, bufA, N);
        k_selfinit<<<gNH4, blk, 0, stream>>>(bufA, dis, bufB, N);
        k_scatter<<<gE4, blk, 0, stream>>>(src, dst, ew, dis, bufA, bufB, E);
        k_bias_relu<<<gNH4, blk, 0, stream>>>(bufB, b1, N);

        k_xw<HID><<<gXW, blk, 0, stream>>>(bufB, W2, bufA, N);
        k_selfinit<<<gNH4, blk, 0, stream>>>(bufA, dis, bufB, N);
        k_scatter<<<gE4, blk, 0, stream>>>(src, dst, ew, dis, bufA, bufB, E);
        k_final<<<gN4, blk, 0, stream>>>(bufB, b2, W3, b3, out, N);
    }
}